// Round 1
// baseline (814.715 us; speedup 1.0000x reference)
//
#include <hip/hip_runtime.h>
#include <hip/hip_bf16.h>

#define NN 50000
#define NE 1600000
#define DIM 128
#define NG 64
#define EPSV 1e-5f
#define NCHUNK 49   // ceil(50000/1024)

typedef __attribute__((ext_vector_type(8))) __bf16 bf16x8;
typedef __attribute__((ext_vector_type(16))) float f32x16;

// ---------------- CSR build ----------------

__global__ void count_kernel(const int* __restrict__ ecol, int* __restrict__ cnt) {
    int e = blockIdx.x * 256 + threadIdx.x;
    if (e < NE) atomicAdd(&cnt[ecol[e]], 1);
}

__global__ void scan_chunk(const int* __restrict__ cnt, int* __restrict__ excl,
                           int* __restrict__ csum) {
    __shared__ int lds[256];
    int t = threadIdx.x;
    int base = blockIdx.x * 1024 + t * 4;
    int v0 = (base + 0 < NN) ? cnt[base + 0] : 0;
    int v1 = (base + 1 < NN) ? cnt[base + 1] : 0;
    int v2 = (base + 2 < NN) ? cnt[base + 2] : 0;
    int v3 = (base + 3 < NN) ? cnt[base + 3] : 0;
    int s = v0 + v1 + v2 + v3;
    lds[t] = s;
    __syncthreads();
    for (int off = 1; off < 256; off <<= 1) {
        int x = (t >= off) ? lds[t - off] : 0;
        __syncthreads();
        lds[t] += x;
        __syncthreads();
    }
    int run = lds[t] - s;           // exclusive prefix within chunk
    if (t == 255) csum[blockIdx.x] = lds[t];
    if (base + 0 < NN) excl[base + 0] = run; run += v0;
    if (base + 1 < NN) excl[base + 1] = run; run += v1;
    if (base + 2 < NN) excl[base + 2] = run; run += v2;
    if (base + 3 < NN) excl[base + 3] = run;
}

__global__ void scan_tail(const int* __restrict__ csum, int* __restrict__ coff, int nch) {
    int l = threadIdx.x;
    int v = (l < nch) ? csum[l] : 0;
    int s = v;
    for (int o = 1; o < 64; o <<= 1) {
        int x = __shfl_up(s, o);
        if (l >= o) s += x;
    }
    if (l < nch) coff[l] = s - v;   // exclusive chunk offsets
}

__global__ void fixup_kernel(int* __restrict__ row_ptr, const int* __restrict__ coff,
                             const int* __restrict__ cnt, float* __restrict__ dinv,
                             int* __restrict__ cursor) {
    int n = blockIdx.x * 256 + threadIdx.x;
    if (n < NN) {
        int rp = row_ptr[n] + coff[n >> 10];
        row_ptr[n] = rp;
        cursor[n] = rp;
        dinv[n] = rsqrtf((float)(cnt[n] + 1));   // +1 for self-loop
    }
    if (n == 0) row_ptr[NN] = NE;
}

__global__ void fill_kernel(const int* __restrict__ erow, const int* __restrict__ ecol,
                            const float* __restrict__ dinv, int* __restrict__ cursor,
                            int* __restrict__ esrc, float* __restrict__ enorm) {
    int e = blockIdx.x * 256 + threadIdx.x;
    if (e < NE) {
        int r = erow[e], c = ecol[e];
        int pos = atomicAdd(&cursor[c], 1);
        esrc[pos] = r;
        enorm[pos] = dinv[r] * dinv[c];
    }
}

// ---------------- dense: h @ W -> bf16 table ----------------
// One block = 4 waves; wave w owns 32 output cols [32w,32w+32). B (=W slice)
// lives permanently in registers; grid-strides over 32-row tiles.

__global__ void __launch_bounds__(256) matmul_kernel(const float* __restrict__ h,
                                                     const float* __restrict__ W,
                                                     __bf16* __restrict__ t) {
    const int wave = threadIdx.x >> 6;
    const int lane = threadIdx.x & 63;
    const int col = wave * 32 + (lane & 31);
    const int khalf = (lane >> 5) * 8;   // 0 or 8

    bf16x8 b[8];
#pragma unroll
    for (int kc = 0; kc < 8; kc++) {
#pragma unroll
        for (int j = 0; j < 8; j++) {
            b[kc][j] = (__bf16)W[(kc * 16 + khalf + j) * DIM + col];
        }
    }

    const int ntiles = (NN + 31) / 32;
    for (int tile = blockIdx.x; tile < ntiles; tile += gridDim.x) {
        const int arow = tile * 32 + (lane & 31);
        const int arow_c = (arow < NN) ? arow : (NN - 1);  // clamped load; bad rows not stored
        f32x16 acc = {};
#pragma unroll
        for (int kc = 0; kc < 8; kc++) {
            const float4* p = (const float4*)(h + (size_t)arow_c * DIM + kc * 16 + khalf);
            float4 lo = p[0], hi = p[1];
            bf16x8 a;
            a[0] = (__bf16)lo.x; a[1] = (__bf16)lo.y; a[2] = (__bf16)lo.z; a[3] = (__bf16)lo.w;
            a[4] = (__bf16)hi.x; a[5] = (__bf16)hi.y; a[6] = (__bf16)hi.z; a[7] = (__bf16)hi.w;
            acc = __builtin_amdgcn_mfma_f32_32x32x16_bf16(a, b[kc], acc, 0, 0, 0);
        }
#pragma unroll
        for (int r = 0; r < 16; r++) {
            int orow = tile * 32 + (r & 3) + 8 * (r >> 2) + 4 * (lane >> 5);
            if (orow < NN) t[(size_t)orow * DIM + col] = (__bf16)acc[r];
        }
    }
}

// ---------------- sparse: pull-gather per node ----------------
// One wave per node; lane handles cols {2*lane, 2*lane+1}; bf16 table read as u32.

__global__ void __launch_bounds__(256) gather_bn_kernel(
    const unsigned int* __restrict__ t32, const int* __restrict__ row_ptr,
    const int* __restrict__ esrc, const float* __restrict__ enorm,
    const float* __restrict__ dinv, const float* __restrict__ bias,
    const float* __restrict__ gamma, const float* __restrict__ beta,
    const float* __restrict__ rmean, const float* __restrict__ rvar,
    float* __restrict__ out) {
    const int lane = threadIdx.x & 63;
    const int n = blockIdx.x * 4 + (threadIdx.x >> 6);
    if (n >= NN) return;
    float ax = 0.f, ay = 0.f;
    const int beg = row_ptr[n], end = row_ptr[n + 1];
    for (int e = beg; e < end; ++e) {
        const int src = esrc[e];
        const float w = enorm[e];
        const unsigned int u = t32[src * 64 + lane];
        ax = fmaf(__uint_as_float(u << 16), w, ax);
        ay = fmaf(__uint_as_float(u & 0xffff0000u), w, ay);
    }
    {   // self loop: norm = dinv[n]^2
        float w = dinv[n]; w *= w;
        const unsigned int u = t32[n * 64 + lane];
        ax = fmaf(__uint_as_float(u << 16), w, ax);
        ay = fmaf(__uint_as_float(u & 0xffff0000u), w, ay);
    }
    const int c0 = lane * 2, c1 = c0 + 1;
    ax += bias[c0]; ay += bias[c1];
    ax = (ax - rmean[c0]) * rsqrtf(rvar[c0] + EPSV) * gamma[c0] + beta[c0];
    ay = (ay - rmean[c1]) * rsqrtf(rvar[c1] + EPSV) * gamma[c1] + beta[c1];
    ax = fmaxf(ax, 0.f); ay = fmaxf(ay, 0.f);
    float2 o; o.x = ax; o.y = ay;
    *(float2*)(out + (size_t)n * DIM + c0) = o;
}

__global__ void __launch_bounds__(256) gather_pool_kernel(
    const unsigned int* __restrict__ t32, const int* __restrict__ row_ptr,
    const int* __restrict__ esrc, const float* __restrict__ enorm,
    const float* __restrict__ dinv, const float* __restrict__ bias,
    const int* __restrict__ batch, float* __restrict__ out) {
    const int lane = threadIdx.x & 63;
    const int n = blockIdx.x * 4 + (threadIdx.x >> 6);
    if (n >= NN) return;
    float ax = 0.f, ay = 0.f;
    const int beg = row_ptr[n], end = row_ptr[n + 1];
    for (int e = beg; e < end; ++e) {
        const int src = esrc[e];
        const float w = enorm[e];
        const unsigned int u = t32[src * 64 + lane];
        ax = fmaf(__uint_as_float(u << 16), w, ax);
        ay = fmaf(__uint_as_float(u & 0xffff0000u), w, ay);
    }
    {
        float w = dinv[n]; w *= w;
        const unsigned int u = t32[n * 64 + lane];
        ax = fmaf(__uint_as_float(u << 16), w, ax);
        ay = fmaf(__uint_as_float(u & 0xffff0000u), w, ay);
    }
    const int c0 = lane * 2, c1 = c0 + 1;
    ax += bias[c0]; ay += bias[c1];
    const int g = batch[n];
    atomicAdd(out + (size_t)g * DIM + c0, ax);
    atomicAdd(out + (size_t)g * DIM + c1, ay);
}

// ---------------- launch ----------------

extern "C" void kernel_launch(void* const* d_in, const int* in_sizes, int n_in,
                              void* d_out, int out_size, void* d_ws, size_t ws_size,
                              hipStream_t stream) {
    const float* x    = (const float*)d_in[0];
    const int*   ei   = (const int*)d_in[1];
    const int*   batch= (const int*)d_in[2];
    const float* W1 = (const float*)d_in[3];
    const float* b1 = (const float*)d_in[4];
    const float* W2 = (const float*)d_in[5];
    const float* b2 = (const float*)d_in[6];
    const float* W3 = (const float*)d_in[7];
    const float* b3 = (const float*)d_in[8];
    const float* g1 = (const float*)d_in[9];
    const float* be1= (const float*)d_in[10];
    const float* rm1= (const float*)d_in[11];
    const float* rv1= (const float*)d_in[12];
    const float* g2 = (const float*)d_in[13];
    const float* be2= (const float*)d_in[14];
    const float* rm2= (const float*)d_in[15];
    const float* rv2= (const float*)d_in[16];
    const int* erow = ei;
    const int* ecol = ei + NE;

    char* ws = (char*)d_ws;
    size_t off = 0;
    auto alloc = [&](size_t bytes) -> void* {
        void* p = ws + off;
        off = (off + bytes + 255) & ~(size_t)255;
        return p;
    };
    int*    cnt     = (int*)alloc(NN * sizeof(int));
    int*    row_ptr = (int*)alloc((NN + 1) * sizeof(int));
    int*    cursor  = (int*)alloc(NN * sizeof(int));
    int*    csum    = (int*)alloc(64 * sizeof(int));
    int*    coff    = (int*)alloc(64 * sizeof(int));
    float*  dinv    = (float*)alloc(NN * sizeof(float));
    int*    esrc    = (int*)alloc(NE * sizeof(int));
    float*  enorm   = (float*)alloc(NE * sizeof(float));
    __bf16* tbuf    = (__bf16*)alloc((size_t)NN * DIM * sizeof(__bf16));
    float*  hbuf    = (float*)alloc((size_t)NN * DIM * sizeof(float));

    hipMemsetAsync(cnt, 0, NN * sizeof(int), stream);
    hipMemsetAsync(d_out, 0, NG * DIM * sizeof(float), stream);

    count_kernel<<<(NE + 255) / 256, 256, 0, stream>>>(ecol, cnt);
    scan_chunk<<<NCHUNK, 256, 0, stream>>>(cnt, row_ptr, csum);
    scan_tail<<<1, 64, 0, stream>>>(csum, coff, NCHUNK);
    fixup_kernel<<<(NN + 255) / 256, 256, 0, stream>>>(row_ptr, coff, cnt, dinv, cursor);
    fill_kernel<<<(NE + 255) / 256, 256, 0, stream>>>(erow, ecol, dinv, cursor, esrc, enorm);

    const unsigned int* t32 = (const unsigned int*)tbuf;

    matmul_kernel<<<512, 256, 0, stream>>>(x, W1, tbuf);
    gather_bn_kernel<<<(NN + 3) / 4, 256, 0, stream>>>(t32, row_ptr, esrc, enorm, dinv,
                                                       b1, g1, be1, rm1, rv1, hbuf);
    matmul_kernel<<<512, 256, 0, stream>>>(hbuf, W2, tbuf);
    gather_bn_kernel<<<(NN + 3) / 4, 256, 0, stream>>>(t32, row_ptr, esrc, enorm, dinv,
                                                       b2, g2, be2, rm2, rv2, hbuf);
    matmul_kernel<<<512, 256, 0, stream>>>(hbuf, W3, tbuf);
    gather_pool_kernel<<<(NN + 3) / 4, 256, 0, stream>>>(t32, row_ptr, esrc, enorm, dinv,
                                                         b3, batch, (float*)d_out);
}

// Round 2
// 499.162 us; speedup vs baseline: 1.6322x; 1.6322x over previous
//
#include <hip/hip_runtime.h>
#include <hip/hip_bf16.h>

#define NN 50000
#define NE 1600000
#define DIM 128
#define NG 64
#define EPSV 1e-5f
#define NCHUNK 49   // ceil(50000/1024)

typedef __attribute__((ext_vector_type(8))) __bf16 bf16x8;
typedef __attribute__((ext_vector_type(16))) float f32x16;

// ---------------- CSR build ----------------

__global__ void count_kernel(const int* __restrict__ ecol, int* __restrict__ cnt) {
    int e = blockIdx.x * 256 + threadIdx.x;
    if (e < NE) atomicAdd(&cnt[ecol[e]], 1);
}

__global__ void scan_chunk(const int* __restrict__ cnt, int* __restrict__ excl,
                           int* __restrict__ csum) {
    __shared__ int lds[256];
    int t = threadIdx.x;
    int base = blockIdx.x * 1024 + t * 4;
    int v0 = (base + 0 < NN) ? cnt[base + 0] : 0;
    int v1 = (base + 1 < NN) ? cnt[base + 1] : 0;
    int v2 = (base + 2 < NN) ? cnt[base + 2] : 0;
    int v3 = (base + 3 < NN) ? cnt[base + 3] : 0;
    int s = v0 + v1 + v2 + v3;
    lds[t] = s;
    __syncthreads();
    for (int off = 1; off < 256; off <<= 1) {
        int x = (t >= off) ? lds[t - off] : 0;
        __syncthreads();
        lds[t] += x;
        __syncthreads();
    }
    int run = lds[t] - s;           // exclusive prefix within chunk
    if (t == 255) csum[blockIdx.x] = lds[t];
    if (base + 0 < NN) excl[base + 0] = run; run += v0;
    if (base + 1 < NN) excl[base + 1] = run; run += v1;
    if (base + 2 < NN) excl[base + 2] = run; run += v2;
    if (base + 3 < NN) excl[base + 3] = run;
}

__global__ void scan_tail(const int* __restrict__ csum, int* __restrict__ coff, int nch) {
    int l = threadIdx.x;
    int v = (l < nch) ? csum[l] : 0;
    int s = v;
    for (int o = 1; o < 64; o <<= 1) {
        int x = __shfl_up(s, o);
        if (l >= o) s += x;
    }
    if (l < nch) coff[l] = s - v;   // exclusive chunk offsets
}

__global__ void fixup_kernel(int* __restrict__ row_ptr, const int* __restrict__ coff,
                             const int* __restrict__ cnt, float* __restrict__ dinv,
                             int* __restrict__ cursor) {
    int n = blockIdx.x * 256 + threadIdx.x;
    if (n < NN) {
        int rp = row_ptr[n] + coff[n >> 10];
        row_ptr[n] = rp;
        cursor[n] = rp;
        dinv[n] = rsqrtf((float)(cnt[n] + 1));   // +1 for self-loop
    }
    if (n == 0) row_ptr[NN] = NE;
}

__global__ void fill_kernel(const int* __restrict__ erow, const int* __restrict__ ecol,
                            const float* __restrict__ dinv, int* __restrict__ cursor,
                            int* __restrict__ esrc, float* __restrict__ enorm) {
    int e = blockIdx.x * 256 + threadIdx.x;
    if (e < NE) {
        int r = erow[e], c = ecol[e];
        int pos = atomicAdd(&cursor[c], 1);
        esrc[pos] = r;
        enorm[pos] = dinv[r] * dinv[c];
    }
}

// ---------------- dense: h @ W -> bf16 table ----------------

__global__ void __launch_bounds__(256) matmul_kernel(const float* __restrict__ h,
                                                     const float* __restrict__ W,
                                                     __bf16* __restrict__ t) {
    const int wave = threadIdx.x >> 6;
    const int lane = threadIdx.x & 63;
    const int col = wave * 32 + (lane & 31);
    const int khalf = (lane >> 5) * 8;   // 0 or 8

    bf16x8 b[8];
#pragma unroll
    for (int kc = 0; kc < 8; kc++) {
#pragma unroll
        for (int j = 0; j < 8; j++) {
            b[kc][j] = (__bf16)W[(kc * 16 + khalf + j) * DIM + col];
        }
    }

    const int ntiles = (NN + 31) / 32;
    for (int tile = blockIdx.x; tile < ntiles; tile += gridDim.x) {
        const int arow = tile * 32 + (lane & 31);
        const int arow_c = (arow < NN) ? arow : (NN - 1);  // clamped load; bad rows not stored
        f32x16 acc = {};
#pragma unroll
        for (int kc = 0; kc < 8; kc++) {
            const float4* p = (const float4*)(h + (size_t)arow_c * DIM + kc * 16 + khalf);
            float4 lo = p[0], hi = p[1];
            bf16x8 a;
            a[0] = (__bf16)lo.x; a[1] = (__bf16)lo.y; a[2] = (__bf16)lo.z; a[3] = (__bf16)lo.w;
            a[4] = (__bf16)hi.x; a[5] = (__bf16)hi.y; a[6] = (__bf16)hi.z; a[7] = (__bf16)hi.w;
            acc = __builtin_amdgcn_mfma_f32_32x32x16_bf16(a, b[kc], acc, 0, 0, 0);
        }
#pragma unroll
        for (int r = 0; r < 16; r++) {
            int orow = tile * 32 + (r & 3) + 8 * (r >> 2) + 4 * (lane >> 5);
            if (orow < NN) t[(size_t)orow * DIM + col] = (__bf16)acc[r];
        }
    }
}

// ---------------- sparse: pull-gather per node ----------------
// One wave per node; lane handles cols {2*lane, 2*lane+1}; bf16 table read as u32.
// Node index is forced into an SGPR so row_ptr/esrc/enorm become scalar loads;
// the edge loop is unrolled 8-wide with predication (w=0 lanes re-read edge beg)
// so 8 independent table loads are in flight per wave.

#define UNROLL 8

__device__ __forceinline__ void gather_core(
    const unsigned int* __restrict__ t32, const int* __restrict__ esrc,
    const float* __restrict__ enorm, int beg, int end, int lane,
    float& ax, float& ay) {
    for (int e = beg; e < end; e += UNROLL) {
        int   s[UNROLL];
        float w[UNROLL];
        unsigned int u[UNROLL];
#pragma unroll
        for (int i = 0; i < UNROLL; i++) {
            const bool ok = (e + i) < end;
            const int  ee = ok ? (e + i) : beg;
            s[i] = esrc[ee];
            w[i] = ok ? enorm[ee] : 0.f;
        }
#pragma unroll
        for (int i = 0; i < UNROLL; i++) u[i] = t32[(size_t)s[i] * 64 + lane];
#pragma unroll
        for (int i = 0; i < UNROLL; i++) {
            ax = fmaf(__uint_as_float(u[i] << 16), w[i], ax);
            ay = fmaf(__uint_as_float(u[i] & 0xffff0000u), w[i], ay);
        }
    }
}

__global__ void __launch_bounds__(256) gather_bn_kernel(
    const unsigned int* __restrict__ t32, const int* __restrict__ row_ptr,
    const int* __restrict__ esrc, const float* __restrict__ enorm,
    const float* __restrict__ dinv, const float* __restrict__ bias,
    const float* __restrict__ gamma, const float* __restrict__ beta,
    const float* __restrict__ rmean, const float* __restrict__ rvar,
    float* __restrict__ out) {
    const int lane = threadIdx.x & 63;
    const int n = __builtin_amdgcn_readfirstlane(blockIdx.x * 4 + (threadIdx.x >> 6));
    if (n >= NN) return;
    float ax = 0.f, ay = 0.f;
    const int beg = row_ptr[n], end = row_ptr[n + 1];
    gather_core(t32, esrc, enorm, beg, end, lane, ax, ay);
    {   // self loop: norm = dinv[n]^2
        float w = dinv[n]; w *= w;
        const unsigned int u = t32[(size_t)n * 64 + lane];
        ax = fmaf(__uint_as_float(u << 16), w, ax);
        ay = fmaf(__uint_as_float(u & 0xffff0000u), w, ay);
    }
    const int c0 = lane * 2, c1 = c0 + 1;
    ax += bias[c0]; ay += bias[c1];
    ax = (ax - rmean[c0]) * rsqrtf(rvar[c0] + EPSV) * gamma[c0] + beta[c0];
    ay = (ay - rmean[c1]) * rsqrtf(rvar[c1] + EPSV) * gamma[c1] + beta[c1];
    ax = fmaxf(ax, 0.f); ay = fmaxf(ay, 0.f);
    float2 o; o.x = ax; o.y = ay;
    *(float2*)(out + (size_t)n * DIM + c0) = o;
}

__global__ void __launch_bounds__(256) gather_pool_kernel(
    const unsigned int* __restrict__ t32, const int* __restrict__ row_ptr,
    const int* __restrict__ esrc, const float* __restrict__ enorm,
    const float* __restrict__ dinv, const float* __restrict__ bias,
    const int* __restrict__ batch, float* __restrict__ out) {
    const int lane = threadIdx.x & 63;
    const int n = __builtin_amdgcn_readfirstlane(blockIdx.x * 4 + (threadIdx.x >> 6));
    if (n >= NN) return;
    float ax = 0.f, ay = 0.f;
    const int beg = row_ptr[n], end = row_ptr[n + 1];
    gather_core(t32, esrc, enorm, beg, end, lane, ax, ay);
    {
        float w = dinv[n]; w *= w;
        const unsigned int u = t32[(size_t)n * 64 + lane];
        ax = fmaf(__uint_as_float(u << 16), w, ax);
        ay = fmaf(__uint_as_float(u & 0xffff0000u), w, ay);
    }
    const int c0 = lane * 2, c1 = c0 + 1;
    ax += bias[c0]; ay += bias[c1];
    const int g = batch[n];
    atomicAdd(out + (size_t)g * DIM + c0, ax);
    atomicAdd(out + (size_t)g * DIM + c1, ay);
}

// ---------------- launch ----------------

extern "C" void kernel_launch(void* const* d_in, const int* in_sizes, int n_in,
                              void* d_out, int out_size, void* d_ws, size_t ws_size,
                              hipStream_t stream) {
    const float* x    = (const float*)d_in[0];
    const int*   ei   = (const int*)d_in[1];
    const int*   batch= (const int*)d_in[2];
    const float* W1 = (const float*)d_in[3];
    const float* b1 = (const float*)d_in[4];
    const float* W2 = (const float*)d_in[5];
    const float* b2 = (const float*)d_in[6];
    const float* W3 = (const float*)d_in[7];
    const float* b3 = (const float*)d_in[8];
    const float* g1 = (const float*)d_in[9];
    const float* be1= (const float*)d_in[10];
    const float* rm1= (const float*)d_in[11];
    const float* rv1= (const float*)d_in[12];
    const float* g2 = (const float*)d_in[13];
    const float* be2= (const float*)d_in[14];
    const float* rm2= (const float*)d_in[15];
    const float* rv2= (const float*)d_in[16];
    const int* erow = ei;
    const int* ecol = ei + NE;

    char* ws = (char*)d_ws;
    size_t off = 0;
    auto alloc = [&](size_t bytes) -> void* {
        void* p = ws + off;
        off = (off + bytes + 255) & ~(size_t)255;
        return p;
    };
    int*    cnt     = (int*)alloc(NN * sizeof(int));
    int*    row_ptr = (int*)alloc((NN + 1) * sizeof(int));
    int*    cursor  = (int*)alloc(NN * sizeof(int));
    int*    csum    = (int*)alloc(64 * sizeof(int));
    int*    coff    = (int*)alloc(64 * sizeof(int));
    float*  dinv    = (float*)alloc(NN * sizeof(float));
    int*    esrc    = (int*)alloc(NE * sizeof(int));
    float*  enorm   = (float*)alloc(NE * sizeof(float));
    __bf16* tbuf    = (__bf16*)alloc((size_t)NN * DIM * sizeof(__bf16));
    float*  hbuf    = (float*)alloc((size_t)NN * DIM * sizeof(float));

    hipMemsetAsync(cnt, 0, NN * sizeof(int), stream);
    hipMemsetAsync(d_out, 0, NG * DIM * sizeof(float), stream);

    count_kernel<<<(NE + 255) / 256, 256, 0, stream>>>(ecol, cnt);
    scan_chunk<<<NCHUNK, 256, 0, stream>>>(cnt, row_ptr, csum);
    scan_tail<<<1, 64, 0, stream>>>(csum, coff, NCHUNK);
    fixup_kernel<<<(NN + 255) / 256, 256, 0, stream>>>(row_ptr, coff, cnt, dinv, cursor);
    fill_kernel<<<(NE + 255) / 256, 256, 0, stream>>>(erow, ecol, dinv, cursor, esrc, enorm);

    const unsigned int* t32 = (const unsigned int*)tbuf;

    matmul_kernel<<<512, 256, 0, stream>>>(x, W1, tbuf);
    gather_bn_kernel<<<(NN + 3) / 4, 256, 0, stream>>>(t32, row_ptr, esrc, enorm, dinv,
                                                       b1, g1, be1, rm1, rv1, hbuf);
    matmul_kernel<<<512, 256, 0, stream>>>(hbuf, W2, tbuf);
    gather_bn_kernel<<<(NN + 3) / 4, 256, 0, stream>>>(t32, row_ptr, esrc, enorm, dinv,
                                                       b2, g2, be2, rm2, rv2, hbuf);
    matmul_kernel<<<512, 256, 0, stream>>>(hbuf, W3, tbuf);
    gather_pool_kernel<<<(NN + 3) / 4, 256, 0, stream>>>(t32, row_ptr, esrc, enorm, dinv,
                                                         b3, batch, (float*)d_out);
}